// Round 3
// baseline (443.392 us; speedup 1.0000x reference)
//
#include <hip/hip_runtime.h>
#include <stdint.h>

// ---------- types ----------
typedef short bf16x8   __attribute__((ext_vector_type(8)));
typedef short short4v  __attribute__((ext_vector_type(4)));
typedef short short8v  __attribute__((ext_vector_type(8)));
typedef float f32x4    __attribute__((ext_vector_type(4)));

typedef __attribute__((address_space(3))) uint32_t lds_u32;
typedef const __attribute__((address_space(1))) uint32_t glob_u32;

__device__ __forceinline__ void gl_lds16(const void* g, void* l) {
  __builtin_amdgcn_global_load_lds((glob_u32*)g, (lds_u32*)l, 16, 0, 0);
}

__device__ __forceinline__ float bf2f(short u) {
  union { float f; uint32_t i; } v; v.i = ((uint32_t)(uint16_t)u) << 16; return v.f;
}
__device__ __forceinline__ short f2bf(float f) {
  union { float f; uint32_t i; } v; v.f = f;
  uint32_t r = v.i + 0x7FFFu + ((v.i >> 16) & 1u);
  return (short)(r >> 16);
}
__device__ __forceinline__ float siluf(float x) {
  return x * __builtin_amdgcn_rcpf(1.0f + __expf(-x));
}
__device__ __forceinline__ f32x4 mfma16(bf16x8 a, bf16x8 b, f32x4 c) {
  return __builtin_amdgcn_mfma_f32_16x16x32_bf16(a, b, c, 0, 0, 0);
}

// ---------- K1: LayerNorm(x) -> bf16 ----------
__global__ __launch_bounds__(256) void k_ln(const float* __restrict__ x, short* __restrict__ xn) {
  int row = blockIdx.x * 4 + (threadIdx.x >> 6);
  int lane = threadIdx.x & 63;
  const float4* xr = (const float4*)(x + (size_t)row * 512);
  float4 a = xr[lane * 2], b = xr[lane * 2 + 1];
  float s  = a.x + a.y + a.z + a.w + b.x + b.y + b.z + b.w;
  float s2 = a.x*a.x + a.y*a.y + a.z*a.z + a.w*a.w + b.x*b.x + b.y*b.y + b.z*b.z + b.w*b.w;
#pragma unroll
  for (int m = 1; m < 64; m <<= 1) { s += __shfl_xor(s, m); s2 += __shfl_xor(s2, m); }
  float mu = s * (1.f / 512.f);
  float rstd = rsqrtf(s2 * (1.f / 512.f) - mu * mu + 1e-6f);
  float v[8] = {a.x, a.y, a.z, a.w, b.x, b.y, b.z, b.w};
  short8v o;
#pragma unroll
  for (int j = 0; j < 8; ++j) o[j] = f2bf((v[j] - mu) * rstd);
  *(short8v*)&xn[(size_t)row * 512 + lane * 8] = o;
}

// ---------- K2: transpose+cast uvqk (512x2048) -> Wt (2048x512) bf16 ----------
__global__ __launch_bounds__(256) void k_prep_w(const float* __restrict__ uvqk, short* __restrict__ Wt) {
  __shared__ float t[64][65];
  int k0 = blockIdx.x * 64;
  int c0 = blockIdx.y * 64;
  for (int i = threadIdx.x; i < 64 * 64; i += 256) {
    int r = i >> 6, c = i & 63;
    t[r][c] = uvqk[(size_t)(k0 + r) * 2048 + c0 + c];
  }
  __syncthreads();
  for (int i = threadIdx.x; i < 64 * 64; i += 256) {
    int c = i >> 6, k = i & 63;
    Wt[(size_t)(c0 + c) * 512 + k0 + k] = f2bf(t[k][c]);
  }
}

// ---------- K2b: cast o_w ----------
__global__ __launch_bounds__(256) void k_cast_ow(const float* __restrict__ ow, short* __restrict__ owt) {
  int i = blockIdx.x * 256 + threadIdx.x;
  owt[i] = f2bf(ow[i]);
}

// ---------- shared GEMM core: 128x128 tile, K=512, BK=64, 4 waves ----------
__device__ __forceinline__ void gemm_core(const short* __restrict__ A, const short* __restrict__ Bt,
                                          int t0, int c0, short* As, short* Bs, f32x4 (&acc)[4][4]) {
  int tid = threadIdx.x;
  int w = tid >> 6, lane = tid & 63, l16 = lane & 15, lq = lane >> 4;
  int wm = (w >> 1) * 64, wn = (w & 1) * 64;
  int srow = tid >> 3;
  int sch = (tid & 7) ^ (srow & 7);
  const short* ag = A  + (size_t)(t0 + srow) * 512 + sch * 8;
  const short* bg = Bt + (size_t)(c0 + srow) * 512 + sch * 8;

  for (int k0 = 0; k0 < 512; k0 += 64) {
#pragma unroll
    for (int j = 0; j < 4; ++j) {
      gl_lds16(ag + (size_t)j * 32 * 512 + k0, (char*)As + j * 4096 + w * 1024);
      gl_lds16(bg + (size_t)j * 32 * 512 + k0, (char*)Bs + j * 4096 + w * 1024);
    }
    asm volatile("s_waitcnt vmcnt(0)" ::: "memory");
    __syncthreads();
#pragma unroll
    for (int kk = 0; kk < 2; ++kk) {
      bf16x8 af[4], bf[4];
#pragma unroll
      for (int mi = 0; mi < 4; ++mi) {
        int row = wm + mi * 16 + l16;
        af[mi] = *(const bf16x8*)&As[row * 64 + (((kk * 4 + lq) ^ (l16 & 7)) * 8)];
      }
#pragma unroll
      for (int ni = 0; ni < 4; ++ni) {
        int row = wn + ni * 16 + l16;
        bf[ni] = *(const bf16x8*)&Bs[row * 64 + (((kk * 4 + lq) ^ (l16 & 7)) * 8)];
      }
#pragma unroll
      for (int mi = 0; mi < 4; ++mi)
#pragma unroll
        for (int ni = 0; ni < 4; ++ni)
          acc[mi][ni] = mfma16(af[mi], bf[ni], acc[mi][ni]);
    }
    __syncthreads();
  }
}

// ---------- K3: proj = silu(xn @ Wt^T); v written transposed to Vt[b,h,d,n] ----------
__global__ __launch_bounds__(256) void k_gemm1(const short* __restrict__ A, const short* __restrict__ Bt,
                                               short* __restrict__ proj, short* __restrict__ Vt) {
  __shared__ short As[128 * 64], Bs[128 * 64];
  int c0 = blockIdx.x * 128, t0 = blockIdx.y * 128;
  f32x4 acc[4][4] = {};
  gemm_core(A, Bt, t0, c0, As, Bs, acc);
  int tid = threadIdx.x, w = tid >> 6, lane = tid & 63, l16 = lane & 15, lq = lane >> 4;
  int wm = (w >> 1) * 64, wn = (w & 1) * 64;
  bool isv = (c0 >= 512 && c0 < 1024);
#pragma unroll
  for (int mi = 0; mi < 4; ++mi)
#pragma unroll
    for (int ni = 0; ni < 4; ++ni) {
      int c = c0 + wn + ni * 16 + l16;
      int trow = t0 + wm + mi * 16 + lq * 4;
      if (isv) {
        int hh = (c - 512) >> 6, d = (c - 512) & 63;
        int bb = trow >> 11, nn = trow & 2047;
        short4v pv;
#pragma unroll
        for (int i = 0; i < 4; ++i) pv[i] = f2bf(siluf(acc[mi][ni][i]));
        *(short4v*)&Vt[((size_t)(bb * 8 + hh) * 64 + d) * 2048 + nn] = pv;
      } else {
#pragma unroll
        for (int i = 0; i < 4; ++i)
          proj[(size_t)(trow + i) * 2048 + c] = f2bf(siluf(acc[mi][ni][i]));
      }
    }
}

// ---------- K4: fused attention (pipelined, Sr-free) ----------
// BQ=128 (32 q-rows/wave), BKV=64. Double-buffered K/V via gl_lds.
// Epilogue runs in D-fragment layout on s regs; rpb/mask scalar-prefetched.
// Ps rows are wave-private -> no barrier between Ps write and PV read.
// One block-barrier per iteration.
__global__ __launch_bounds__(256, 3) void k_attn(const short* __restrict__ proj,
                                                 const short* __restrict__ Vt,
                                                 const float* __restrict__ rpb,
                                                 const float* __restrict__ maskp,
                                                 float* __restrict__ attn) {
  __shared__ __align__(16) short Ks[2][64 * 64];   // [buf][kv][d], chunk ^= row&7
  __shared__ __align__(16) short Vs[2][64 * 64];   // [buf][d][kv], chunk ^= row&7
  __shared__ __align__(16) short Ps[128 * 64];     // [q][k] bf16, chunk ^= row&7

  int p = blockIdx.x;
  int L = (p & 7) * 128 + (p >> 3);   // chunked XCD swizzle: XCD shares both rpb (h) and mask (b) slices
  int qt = L >> 6, h = (L >> 3) & 7, b = L & 7;
  int n0 = qt * 128;

  int tid = threadIdx.x;
  int w = tid >> 6, lane = tid & 63, l16 = lane & 15, lq = lane >> 4;

  // Q fragments in registers for whole block
  bf16x8 qf[2][2];
#pragma unroll
  for (int mi = 0; mi < 2; ++mi)
#pragma unroll
    for (int kk = 0; kk < 2; ++kk) {
      int n = n0 + w * 32 + mi * 16 + l16;
      qf[mi][kk] = *(const bf16x8*)&proj[(size_t)(b * 2048 + n) * 2048 + 1024 + h * 64 + kk * 32 + lq * 8];
    }

  // staging lane constants
  int j8 = lane >> 3, c8 = lane & 7;
  int srcc = (c8 ^ j8) * 8;                     // pre-swizzled source 16B-chunk
  const short* kg = proj + (size_t)(b * 2048) * 2048 + 1536 + h * 64 + srcc;
  const short* vg = Vt + (size_t)((b * 8 + h) * 64) * 2048 + srcc;

  // rpb/mask per-thread base (D-fragment layout: row = w*32+mi*16+lq*4+i, col = ni*16+l16)
  const float* rp_t = rpb   + (size_t)h * 4194304 + (size_t)(n0 + w * 32 + lq * 4) * 2048 + l16;
  const float* mk_t = maskp + (size_t)b * 4194304 + (size_t)(n0 + w * 32 + lq * 4) * 2048 + l16;

  f32x4 acc_o[2][4] = {};

  // prologue: stage buffer 0
#pragma unroll
  for (int j = 0; j < 2; ++j) {
    gl_lds16(kg + (size_t)(w * 16 + j * 8 + j8) * 2048, &Ks[0][w * 1024 + j * 512]);
    gl_lds16(vg + (size_t)(w * 16 + j * 8 + j8) * 2048, &Vs[0][w * 1024 + j * 512]);
  }
  asm volatile("s_waitcnt vmcnt(0)" ::: "memory");
  __builtin_amdgcn_s_barrier();

  for (int t = 0; t < 32; ++t) {
    int kv0 = t << 6;
    const short* Kc = Ks[t & 1];
    const short* Vc = Vs[t & 1];
    short* Kn = Ks[(t & 1) ^ 1];
    short* Vn = Vs[(t & 1) ^ 1];
    int kvn = (kv0 + 64) & 2047;     // t=31 restages tile 0 (never consumed)

    // stage next K/V tile
#pragma unroll
    for (int j = 0; j < 2; ++j) {
      gl_lds16(kg + (size_t)(kvn + w * 16 + j * 8 + j8) * 2048, &Kn[w * 1024 + j * 512]);
      gl_lds16(vg + (size_t)(w * 16 + j * 8 + j8) * 2048 + kvn, &Vn[w * 1024 + j * 512]);
    }

    // prefetch rpb/mask stripe 0 (latency hides under QK^T)
    const float* rp_i = rp_t + kv0;
    const float* mk_i = mk_t + kv0;
    float rv0[4][4], mv0[4][4];
#pragma unroll
    for (int ni = 0; ni < 4; ++ni)
#pragma unroll
      for (int i = 0; i < 4; ++i) {
        rv0[ni][i] = rp_i[(size_t)i * 2048 + ni * 16];
        mv0[ni][i] = mk_i[(size_t)i * 2048 + ni * 16];
      }

    // QK^T
    f32x4 s[2][4] = {};
#pragma unroll
    for (int kk = 0; kk < 2; ++kk) {
      bf16x8 kf[4];
#pragma unroll
      for (int ni = 0; ni < 4; ++ni)
        kf[ni] = *(const bf16x8*)&Kc[(ni * 16 + l16) * 64 + (((kk * 4 + lq) ^ (l16 & 7)) * 8)];
#pragma unroll
      for (int mi = 0; mi < 2; ++mi)
#pragma unroll
        for (int ni = 0; ni < 4; ++ni)
          s[mi][ni] = mfma16(qf[mi][kk], kf[ni], s[mi][ni]);
    }

    // prefetch rpb/mask stripe 1 (hides under epilogue stripe 0)
    float rv1[4][4], mv1[4][4];
#pragma unroll
    for (int ni = 0; ni < 4; ++ni)
#pragma unroll
      for (int i = 0; i < 4; ++i) {
        rv1[ni][i] = rp_i[(size_t)(16 + i) * 2048 + ni * 16];
        mv1[ni][i] = mk_i[(size_t)(16 + i) * 2048 + ni * 16];
      }

    // epilogue stripe 0: s + rpb, silu, *mask -> Ps (scalar u16, swizzled)
#pragma unroll
    for (int ni = 0; ni < 4; ++ni)
#pragma unroll
      for (int i = 0; i < 4; ++i) {
        float xx = s[0][ni][i] + rv0[ni][i];
        float pv = siluf(xx) * mv0[ni][i];
        int row = w * 32 + lq * 4 + i;
        int cb = ni * 2 + (l16 >> 3);
        *(short*)((char*)Ps + row * 128 + (((cb ^ (row & 7)) << 4) + (l16 & 7) * 2)) = f2bf(pv);
      }
    // epilogue stripe 1
#pragma unroll
    for (int ni = 0; ni < 4; ++ni)
#pragma unroll
      for (int i = 0; i < 4; ++i) {
        float xx = s[1][ni][i] + rv1[ni][i];
        float pv = siluf(xx) * mv1[ni][i];
        int row = w * 32 + 16 + lq * 4 + i;
        int cb = ni * 2 + (l16 >> 3);
        *(short*)((char*)Ps + row * 128 + (((cb ^ (row & 7)) << 4) + (l16 & 7) * 2)) = f2bf(pv);
      }

    // PV (Ps rows are wave-private; compiler inserts the lgkmcnt)
#pragma unroll
    for (int ks = 0; ks < 2; ++ks) {
      bf16x8 pf[2], vf[4];
#pragma unroll
      for (int mi = 0; mi < 2; ++mi) {
        int rp = w * 32 + mi * 16 + l16;
        pf[mi] = *(const bf16x8*)((const char*)Ps + rp * 128 + (((ks * 4 + lq) ^ (rp & 7)) * 16));
      }
#pragma unroll
      for (int ni = 0; ni < 4; ++ni)
        vf[ni] = *(const bf16x8*)&Vc[(ni * 16 + l16) * 64 + (((ks * 4 + lq) ^ (l16 & 7)) * 8)];
#pragma unroll
      for (int mi = 0; mi < 2; ++mi)
#pragma unroll
        for (int ni = 0; ni < 4; ++ni)
          acc_o[mi][ni] = mfma16(pf[mi], vf[ni], acc_o[mi][ni]);
    }

    // next buffer staged (loads issued ~full phase ago) + all waves done with cur
    asm volatile("s_waitcnt vmcnt(0)" ::: "memory");
    __builtin_amdgcn_s_barrier();
  }

#pragma unroll
  for (int mi = 0; mi < 2; ++mi)
#pragma unroll
    for (int ni = 0; ni < 4; ++ni)
#pragma unroll
      for (int i = 0; i < 4; ++i) {
        int n = n0 + w * 32 + mi * 16 + lq * 4 + i;
        attn[(size_t)(b * 2048 + n) * 512 + h * 64 + ni * 16 + l16] = acc_o[mi][ni][i];
      }
}

// ---------- K5: gated = u * LayerNorm(attn) -> bf16 ----------
__global__ __launch_bounds__(256) void k_gate(const float* __restrict__ attn, const short* __restrict__ proj,
                                              short* __restrict__ gated) {
  int row = blockIdx.x * 4 + (threadIdx.x >> 6);
  int lane = threadIdx.x & 63;
  const float4* ar = (const float4*)(attn + (size_t)row * 512);
  float4 a = ar[lane * 2], b = ar[lane * 2 + 1];
  float s  = a.x + a.y + a.z + a.w + b.x + b.y + b.z + b.w;
  float s2 = a.x*a.x + a.y*a.y + a.z*a.z + a.w*a.w + b.x*b.x + b.y*b.y + b.z*b.z + b.w*b.w;
#pragma unroll
  for (int m = 1; m < 64; m <<= 1) { s += __shfl_xor(s, m); s2 += __shfl_xor(s2, m); }
  float mu = s * (1.f / 512.f);
  float rstd = rsqrtf(s2 * (1.f / 512.f) - mu * mu + 1e-6f);
  float v[8] = {a.x, a.y, a.z, a.w, b.x, b.y, b.z, b.w};
  short8v u = *(const short8v*)&proj[(size_t)row * 2048 + lane * 8];
  short8v g;
#pragma unroll
  for (int j = 0; j < 8; ++j) g[j] = f2bf(bf2f(u[j]) * ((v[j] - mu) * rstd));
  *(short8v*)&gated[(size_t)row * 512 + lane * 8] = g;
}

// ---------- K6: out = gated @ owt^T + o_b + x ----------
__global__ __launch_bounds__(256) void k_gemm2(const short* __restrict__ A, const short* __restrict__ Bt,
                                               const float* __restrict__ ob, const float* __restrict__ x,
                                               float* __restrict__ out) {
  __shared__ short As[128 * 64], Bs[128 * 64];
  int c0 = blockIdx.x * 128, t0 = blockIdx.y * 128;
  f32x4 acc[4][4] = {};
  gemm_core(A, Bt, t0, c0, As, Bs, acc);
  int tid = threadIdx.x, w = tid >> 6, lane = tid & 63, l16 = lane & 15, lq = lane >> 4;
  int wm = (w >> 1) * 64, wn = (w & 1) * 64;
#pragma unroll
  for (int mi = 0; mi < 4; ++mi)
#pragma unroll
    for (int ni = 0; ni < 4; ++ni) {
      int e = c0 + wn + ni * 16 + l16;
      float bias = ob[e];
#pragma unroll
      for (int i = 0; i < 4; ++i) {
        int t = t0 + wm + mi * 16 + lq * 4 + i;
        out[(size_t)t * 512 + e] = acc[mi][ni][i] + bias + x[(size_t)t * 512 + e];
      }
    }
}

// ---------- launch ----------
extern "C" void kernel_launch(void* const* d_in, const int* in_sizes, int n_in,
                              void* d_out, int out_size, void* d_ws, size_t ws_size,
                              hipStream_t stream) {
  const float* x    = (const float*)d_in[0];
  const float* rpb  = (const float*)d_in[1];
  const float* mask = (const float*)d_in[2];
  const float* uvqk = (const float*)d_in[3];
  const float* o_w  = (const float*)d_in[4];
  const float* o_b  = (const float*)d_in[5];
  float* out = (float*)d_out;

  char* p = (char*)d_ws;
  short* xn   = (short*)p; p += 16384ull * 512 * 2;
  short* Wt   = (short*)p; p += 2048ull * 512 * 2;
  short* owt  = (short*)p; p += 512ull * 512 * 2;
  short* proj = (short*)p; p += 16384ull * 2048 * 2;
  short* Vt   = (short*)p; p += 8ull * 8 * 64 * 2048 * 2;
  float* attn = (float*)p; p += 16384ull * 512 * 4;
  short* gated = xn;

  k_ln    <<<4096, 256, 0, stream>>>(x, xn);
  k_prep_w<<<dim3(8, 32), 256, 0, stream>>>(uvqk, Wt);
  k_cast_ow<<<1024, 256, 0, stream>>>(o_w, owt);
  k_gemm1 <<<dim3(16, 128), 256, 0, stream>>>(xn, Wt, proj, Vt);
  k_attn  <<<1024, 256, 0, stream>>>(proj, Vt, rpb, mask, attn);
  k_gate  <<<4096, 256, 0, stream>>>(attn, proj, gated);
  k_gemm2 <<<dim3(4, 128), 256, 0, stream>>>(gated, owt, o_b, x, out);
}

// Round 4
// 392.310 us; speedup vs baseline: 1.1302x; 1.1302x over previous
//
#include <hip/hip_runtime.h>
#include <stdint.h>

// ---------- types ----------
typedef short bf16x8   __attribute__((ext_vector_type(8)));
typedef short short4v  __attribute__((ext_vector_type(4)));
typedef short short8v  __attribute__((ext_vector_type(8)));
typedef float f32x4    __attribute__((ext_vector_type(4)));

typedef __attribute__((address_space(3))) uint32_t lds_u32;
typedef const __attribute__((address_space(1))) uint32_t glob_u32;

__device__ __forceinline__ void gl_lds16(const void* g, void* l) {
  __builtin_amdgcn_global_load_lds((glob_u32*)g, (lds_u32*)l, 16, 0, 0);
}

__device__ __forceinline__ float bf2f(short u) {
  union { float f; uint32_t i; } v; v.i = ((uint32_t)(uint16_t)u) << 16; return v.f;
}
__device__ __forceinline__ short f2bf(float f) {
  union { float f; uint32_t i; } v; v.f = f;
  uint32_t r = v.i + 0x7FFFu + ((v.i >> 16) & 1u);
  return (short)(r >> 16);
}
__device__ __forceinline__ float siluf(float x) {
  return x * __builtin_amdgcn_rcpf(1.0f + __expf(-x));
}
__device__ __forceinline__ f32x4 mfma16(bf16x8 a, bf16x8 b, f32x4 c) {
  return __builtin_amdgcn_mfma_f32_16x16x32_bf16(a, b, c, 0, 0, 0);
}

// ---------- K1: LayerNorm(x) -> bf16 ----------
__global__ __launch_bounds__(256) void k_ln(const float* __restrict__ x, short* __restrict__ xn) {
  int row = blockIdx.x * 4 + (threadIdx.x >> 6);
  int lane = threadIdx.x & 63;
  const float4* xr = (const float4*)(x + (size_t)row * 512);
  float4 a = xr[lane * 2], b = xr[lane * 2 + 1];
  float s  = a.x + a.y + a.z + a.w + b.x + b.y + b.z + b.w;
  float s2 = a.x*a.x + a.y*a.y + a.z*a.z + a.w*a.w + b.x*b.x + b.y*b.y + b.z*b.z + b.w*b.w;
#pragma unroll
  for (int m = 1; m < 64; m <<= 1) { s += __shfl_xor(s, m); s2 += __shfl_xor(s2, m); }
  float mu = s * (1.f / 512.f);
  float rstd = rsqrtf(s2 * (1.f / 512.f) - mu * mu + 1e-6f);
  float v[8] = {a.x, a.y, a.z, a.w, b.x, b.y, b.z, b.w};
  short8v o;
#pragma unroll
  for (int j = 0; j < 8; ++j) o[j] = f2bf((v[j] - mu) * rstd);
  *(short8v*)&xn[(size_t)row * 512 + lane * 8] = o;
}

// ---------- K2: transpose+cast uvqk (512x2048) -> Wt (2048x512) bf16 ----------
__global__ __launch_bounds__(256) void k_prep_w(const float* __restrict__ uvqk, short* __restrict__ Wt) {
  __shared__ float t[64][65];
  int k0 = blockIdx.x * 64;
  int c0 = blockIdx.y * 64;
  for (int i = threadIdx.x; i < 64 * 64; i += 256) {
    int r = i >> 6, c = i & 63;
    t[r][c] = uvqk[(size_t)(k0 + r) * 2048 + c0 + c];
  }
  __syncthreads();
  for (int i = threadIdx.x; i < 64 * 64; i += 256) {
    int c = i >> 6, k = i & 63;
    Wt[(size_t)(c0 + c) * 512 + k0 + k] = f2bf(t[k][c]);
  }
}

// ---------- K2b: cast o_w ----------
__global__ __launch_bounds__(256) void k_cast_ow(const float* __restrict__ ow, short* __restrict__ owt) {
  int i = blockIdx.x * 256 + threadIdx.x;
  owt[i] = f2bf(ow[i]);
}

// ---------- shared GEMM core: 128x128 tile, K=512, BK=64, 4 waves ----------
__device__ __forceinline__ void gemm_core(const short* __restrict__ A, const short* __restrict__ Bt,
                                          int t0, int c0, short* As, short* Bs, f32x4 (&acc)[4][4]) {
  int tid = threadIdx.x;
  int w = tid >> 6, lane = tid & 63, l16 = lane & 15, lq = lane >> 4;
  int wm = (w >> 1) * 64, wn = (w & 1) * 64;
  int srow = tid >> 3;
  int sch = (tid & 7) ^ (srow & 7);
  const short* ag = A  + (size_t)(t0 + srow) * 512 + sch * 8;
  const short* bg = Bt + (size_t)(c0 + srow) * 512 + sch * 8;

  for (int k0 = 0; k0 < 512; k0 += 64) {
#pragma unroll
    for (int j = 0; j < 4; ++j) {
      gl_lds16(ag + (size_t)j * 32 * 512 + k0, (char*)As + j * 4096 + w * 1024);
      gl_lds16(bg + (size_t)j * 32 * 512 + k0, (char*)Bs + j * 4096 + w * 1024);
    }
    asm volatile("s_waitcnt vmcnt(0)" ::: "memory");
    __syncthreads();
#pragma unroll
    for (int kk = 0; kk < 2; ++kk) {
      bf16x8 af[4], bf[4];
#pragma unroll
      for (int mi = 0; mi < 4; ++mi) {
        int row = wm + mi * 16 + l16;
        af[mi] = *(const bf16x8*)&As[row * 64 + (((kk * 4 + lq) ^ (l16 & 7)) * 8)];
      }
#pragma unroll
      for (int ni = 0; ni < 4; ++ni) {
        int row = wn + ni * 16 + l16;
        bf[ni] = *(const bf16x8*)&Bs[row * 64 + (((kk * 4 + lq) ^ (l16 & 7)) * 8)];
      }
#pragma unroll
      for (int mi = 0; mi < 4; ++mi)
#pragma unroll
        for (int ni = 0; ni < 4; ++ni)
          acc[mi][ni] = mfma16(af[mi], bf[ni], acc[mi][ni]);
    }
    __syncthreads();
  }
}

// ---------- K3: proj = silu(xn @ Wt^T); v written transposed to Vt[b,h,d,n] ----------
__global__ __launch_bounds__(256) void k_gemm1(const short* __restrict__ A, const short* __restrict__ Bt,
                                               short* __restrict__ proj, short* __restrict__ Vt) {
  __shared__ short As[128 * 64], Bs[128 * 64];
  int c0 = blockIdx.x * 128, t0 = blockIdx.y * 128;
  f32x4 acc[4][4] = {};
  gemm_core(A, Bt, t0, c0, As, Bs, acc);
  int tid = threadIdx.x, w = tid >> 6, lane = tid & 63, l16 = lane & 15, lq = lane >> 4;
  int wm = (w >> 1) * 64, wn = (w & 1) * 64;
  bool isv = (c0 >= 512 && c0 < 1024);
#pragma unroll
  for (int mi = 0; mi < 4; ++mi)
#pragma unroll
    for (int ni = 0; ni < 4; ++ni) {
      int c = c0 + wn + ni * 16 + l16;
      int trow = t0 + wm + mi * 16 + lq * 4;
      if (isv) {
        int hh = (c - 512) >> 6, d = (c - 512) & 63;
        int bb = trow >> 11, nn = trow & 2047;
        short4v pv;
#pragma unroll
        for (int i = 0; i < 4; ++i) pv[i] = f2bf(siluf(acc[mi][ni][i]));
        *(short4v*)&Vt[((size_t)(bb * 8 + hh) * 64 + d) * 2048 + nn] = pv;
      } else {
#pragma unroll
        for (int i = 0; i < 4; ++i)
          proj[(size_t)(trow + i) * 2048 + c] = f2bf(siluf(acc[mi][ni][i]));
      }
    }
}

// ---------- K4: fused attention (swapped QK^T: S-fragment matches rpb/mask memory order) ----------
// BQ=128 (32 q-rows/wave), BKV=64, double-buffered K/V, 1 barrier/iter.
// mfma(K,Q) -> lane holds S[kv=lq*4+i][q=l16]: rpb/mask are float4 loads along kv.
// P written to wave-private Ps as short4v (8B), XOR-swizzled; PV unchanged.
__global__ __launch_bounds__(256, 3) void k_attn(const short* __restrict__ proj,
                                                 const short* __restrict__ Vt,
                                                 const float* __restrict__ rpb,
                                                 const float* __restrict__ maskp,
                                                 float* __restrict__ attn) {
  __shared__ __align__(16) short Ks[2][64 * 64];   // [buf][kv][d], chunk ^= row&7
  __shared__ __align__(16) short Vs[2][64 * 64];   // [buf][d][kv], chunk ^= row&7
  __shared__ __align__(16) short Ps[128 * 64];     // [q][kv] bf16, 16B-chunk ^= (q&7)

  int p = blockIdx.x;
  int L = (p & 7) * 128 + (p >> 3);   // chunked XCD swizzle
  int qt = L >> 6, h = (L >> 3) & 7, b = L & 7;
  int n0 = qt * 128;

  int tid = threadIdx.x;
  int w = tid >> 6, lane = tid & 63, l16 = lane & 15, lq = lane >> 4;

  // Q fragments (B-operand: col = l16 = q) for whole block
  bf16x8 qf[2][2];
#pragma unroll
  for (int mi = 0; mi < 2; ++mi)
#pragma unroll
    for (int kk = 0; kk < 2; ++kk) {
      int n = n0 + w * 32 + mi * 16 + l16;
      qf[mi][kk] = *(const bf16x8*)&proj[(size_t)(b * 2048 + n) * 2048 + 1024 + h * 64 + kk * 32 + lq * 8];
    }

  // staging lane constants (pre-swizzled global source -> linear LDS dest)
  int j8 = lane >> 3, c8 = lane & 7;
  int srcc = (c8 ^ j8) * 8;
  const short* kg = proj + (size_t)(b * 2048) * 2048 + 1536 + h * 64 + srcc;
  const short* vg = Vt + (size_t)((b * 8 + h) * 64) * 2048 + srcc;

  // rpb/mask per-thread base: row = n0 + w*32 + mi*16 + l16, col = kv0 + ni*16 + lq*4
  const float* rp_t = rpb   + (size_t)h * 4194304 + (size_t)(n0 + w * 32 + l16) * 2048 + lq * 4;
  const float* mk_t = maskp + (size_t)b * 4194304 + (size_t)(n0 + w * 32 + l16) * 2048 + lq * 4;

  f32x4 acc_o[2][4] = {};

  // prologue: stage buffer 0
#pragma unroll
  for (int j = 0; j < 2; ++j) {
    gl_lds16(kg + (size_t)(w * 16 + j * 8 + j8) * 2048, &Ks[0][w * 1024 + j * 512]);
    gl_lds16(vg + (size_t)(w * 16 + j * 8 + j8) * 2048, &Vs[0][w * 1024 + j * 512]);
  }
  asm volatile("s_waitcnt vmcnt(0)" ::: "memory");
  __builtin_amdgcn_s_barrier();

  for (int t = 0; t < 32; ++t) {
    int kv0 = t << 6;
    const short* Kc = Ks[t & 1];
    const short* Vc = Vs[t & 1];

    // stage next K/V tile (skipped on last iter)
    if (t < 31) {
      short* Kn = Ks[(t & 1) ^ 1];
      short* Vn = Vs[(t & 1) ^ 1];
      int kvn = kv0 + 64;
#pragma unroll
      for (int j = 0; j < 2; ++j) {
        gl_lds16(kg + (size_t)(kvn + w * 16 + j * 8 + j8) * 2048, &Kn[w * 1024 + j * 512]);
        gl_lds16(vg + (size_t)(w * 16 + j * 8 + j8) * 2048 + kvn, &Vn[w * 1024 + j * 512]);
      }
    }

    // rpb/mask for q-block 0 (float4, coalesced; latency hides under QK^T)
    f32x4 rv0[4], mv0[4];
#pragma unroll
    for (int ni = 0; ni < 4; ++ni) {
      rv0[ni] = *(const f32x4*)(rp_t + kv0 + ni * 16);
      mv0[ni] = *(const f32x4*)(mk_t + kv0 + ni * 16);
    }

    // QK^T (swapped: A = K rows = kv, B = Q cols = q)
    f32x4 s[4][2];
#pragma unroll
    for (int ni = 0; ni < 4; ++ni)
#pragma unroll
      for (int mi = 0; mi < 2; ++mi) s[ni][mi] = (f32x4){0.f, 0.f, 0.f, 0.f};
    __builtin_amdgcn_s_setprio(1);
#pragma unroll
    for (int kk = 0; kk < 2; ++kk) {
      bf16x8 kf[4];
#pragma unroll
      for (int ni = 0; ni < 4; ++ni)
        kf[ni] = *(const bf16x8*)&Kc[(ni * 16 + l16) * 64 + (((kk * 4 + lq) ^ (l16 & 7)) * 8)];
#pragma unroll
      for (int ni = 0; ni < 4; ++ni)
#pragma unroll
        for (int mi = 0; mi < 2; ++mi)
          s[ni][mi] = mfma16(kf[ni], qf[mi][kk], s[ni][mi]);
    }
    __builtin_amdgcn_s_setprio(0);

    // rpb/mask for q-block 1 (in flight while epilogue 0 runs)
    f32x4 rv1[4], mv1[4];
#pragma unroll
    for (int ni = 0; ni < 4; ++ni) {
      rv1[ni] = *(const f32x4*)(rp_t + 16 * 2048 + kv0 + ni * 16);
      mv1[ni] = *(const f32x4*)(mk_t + 16 * 2048 + kv0 + ni * 16);
    }

    // epilogue q-block 0: p = silu(s + rpb) * mask -> Ps (short4v, swizzled)
    {
      int row = w * 32 + l16;
      char* pr = (char*)Ps + row * 128;
      int swz = (l16 & 7) << 4;
#pragma unroll
      for (int ni = 0; ni < 4; ++ni) {
        short4v pk;
#pragma unroll
        for (int i = 0; i < 4; ++i) {
          float xx = s[ni][0][i] + rv0[ni][i];
          pk[i] = f2bf(siluf(xx) * mv0[ni][i]);
        }
        *(short4v*)(pr + ((ni * 32 + lq * 8) ^ swz)) = pk;
      }
    }
    // epilogue q-block 1
    {
      int row = w * 32 + 16 + l16;
      char* pr = (char*)Ps + row * 128;
      int swz = (l16 & 7) << 4;   // (16+l16)&7 == l16&7
#pragma unroll
      for (int ni = 0; ni < 4; ++ni) {
        short4v pk;
#pragma unroll
        for (int i = 0; i < 4; ++i) {
          float xx = s[ni][1][i] + rv1[ni][i];
          pk[i] = f2bf(siluf(xx) * mv1[ni][i]);
        }
        *(short4v*)(pr + ((ni * 32 + lq * 8) ^ swz)) = pk;
      }
    }

    // PV (Ps rows wave-private; compiler orders LDS deps)
    __builtin_amdgcn_s_setprio(1);
#pragma unroll
    for (int ks = 0; ks < 2; ++ks) {
      bf16x8 pf[2], vf[4];
#pragma unroll
      for (int mi = 0; mi < 2; ++mi) {
        int rp = w * 32 + mi * 16 + l16;
        pf[mi] = *(const bf16x8*)((const char*)Ps + rp * 128 + (((ks * 4 + lq) << 4) ^ ((l16 & 7) << 4)));
      }
#pragma unroll
      for (int ni = 0; ni < 4; ++ni)
        vf[ni] = *(const bf16x8*)&Vc[(ni * 16 + l16) * 64 + (((ks * 4 + lq) ^ (l16 & 7)) * 8)];
#pragma unroll
      for (int mi = 0; mi < 2; ++mi)
#pragma unroll
        for (int ni = 0; ni < 4; ++ni)
          acc_o[mi][ni] = mfma16(pf[mi], vf[ni], acc_o[mi][ni]);
    }
    __builtin_amdgcn_s_setprio(0);

    // next buffer fully staged (loads issued a whole phase ago); all waves done with cur
    asm volatile("s_waitcnt vmcnt(0)" ::: "memory");
    __builtin_amdgcn_s_barrier();
  }

#pragma unroll
  for (int mi = 0; mi < 2; ++mi)
#pragma unroll
    for (int ni = 0; ni < 4; ++ni)
#pragma unroll
      for (int i = 0; i < 4; ++i) {
        int n = n0 + w * 32 + mi * 16 + lq * 4 + i;
        attn[(size_t)(b * 2048 + n) * 512 + h * 64 + ni * 16 + l16] = acc_o[mi][ni][i];
      }
}

// ---------- K5: gated = u * LayerNorm(attn) -> bf16 ----------
__global__ __launch_bounds__(256) void k_gate(const float* __restrict__ attn, const short* __restrict__ proj,
                                              short* __restrict__ gated) {
  int row = blockIdx.x * 4 + (threadIdx.x >> 6);
  int lane = threadIdx.x & 63;
  const float4* ar = (const float4*)(attn + (size_t)row * 512);
  float4 a = ar[lane * 2], b = ar[lane * 2 + 1];
  float s  = a.x + a.y + a.z + a.w + b.x + b.y + b.z + b.w;
  float s2 = a.x*a.x + a.y*a.y + a.z*a.z + a.w*a.w + b.x*b.x + b.y*b.y + b.z*b.z + b.w*b.w;
#pragma unroll
  for (int m = 1; m < 64; m <<= 1) { s += __shfl_xor(s, m); s2 += __shfl_xor(s2, m); }
  float mu = s * (1.f / 512.f);
  float rstd = rsqrtf(s2 * (1.f / 512.f) - mu * mu + 1e-6f);
  float v[8] = {a.x, a.y, a.z, a.w, b.x, b.y, b.z, b.w};
  short8v u = *(const short8v*)&proj[(size_t)row * 2048 + lane * 8];
  short8v g;
#pragma unroll
  for (int j = 0; j < 8; ++j) g[j] = f2bf(bf2f(u[j]) * ((v[j] - mu) * rstd));
  *(short8v*)&gated[(size_t)row * 512 + lane * 8] = g;
}

// ---------- K6: out = gated @ owt^T + o_b + x ----------
__global__ __launch_bounds__(256) void k_gemm2(const short* __restrict__ A, const short* __restrict__ Bt,
                                               const float* __restrict__ ob, const float* __restrict__ x,
                                               float* __restrict__ out) {
  __shared__ short As[128 * 64], Bs[128 * 64];
  int c0 = blockIdx.x * 128, t0 = blockIdx.y * 128;
  f32x4 acc[4][4] = {};
  gemm_core(A, Bt, t0, c0, As, Bs, acc);
  int tid = threadIdx.x, w = tid >> 6, lane = tid & 63, l16 = lane & 15, lq = lane >> 4;
  int wm = (w >> 1) * 64, wn = (w & 1) * 64;
#pragma unroll
  for (int mi = 0; mi < 4; ++mi)
#pragma unroll
    for (int ni = 0; ni < 4; ++ni) {
      int e = c0 + wn + ni * 16 + l16;
      float bias = ob[e];
#pragma unroll
      for (int i = 0; i < 4; ++i) {
        int t = t0 + wm + mi * 16 + lq * 4 + i;
        out[(size_t)t * 512 + e] = acc[mi][ni][i] + bias + x[(size_t)t * 512 + e];
      }
    }
}

// ---------- launch ----------
extern "C" void kernel_launch(void* const* d_in, const int* in_sizes, int n_in,
                              void* d_out, int out_size, void* d_ws, size_t ws_size,
                              hipStream_t stream) {
  const float* x    = (const float*)d_in[0];
  const float* rpb  = (const float*)d_in[1];
  const float* mask = (const float*)d_in[2];
  const float* uvqk = (const float*)d_in[3];
  const float* o_w  = (const float*)d_in[4];
  const float* o_b  = (const float*)d_in[5];
  float* out = (float*)d_out;

  char* p = (char*)d_ws;
  short* xn   = (short*)p; p += 16384ull * 512 * 2;
  short* Wt   = (short*)p; p += 2048ull * 512 * 2;
  short* owt  = (short*)p; p += 512ull * 512 * 2;
  short* proj = (short*)p; p += 16384ull * 2048 * 2;
  short* Vt   = (short*)p; p += 8ull * 8 * 64 * 2048 * 2;
  float* attn = (float*)p; p += 16384ull * 512 * 4;
  short* gated = xn;

  k_ln    <<<4096, 256, 0, stream>>>(x, xn);
  k_prep_w<<<dim3(8, 32), 256, 0, stream>>>(uvqk, Wt);
  k_cast_ow<<<1024, 256, 0, stream>>>(o_w, owt);
  k_gemm1 <<<dim3(16, 128), 256, 0, stream>>>(xn, Wt, proj, Vt);
  k_attn  <<<1024, 256, 0, stream>>>(proj, Vt, rpb, mask, attn);
  k_gate  <<<4096, 256, 0, stream>>>(attn, proj, gated);
  k_gemm2 <<<dim3(4, 128), 256, 0, stream>>>(gated, owt, o_b, x, out);
}